// Round 4
// baseline (217.548 us; speedup 1.0000x reference)
//
#include <hip/hip_runtime.h>
#include <math.h>

// N=1024, X_DIM=HID=Y_DIM=256. Single fused kernel, 256 blocks (1/CU),
// 2 in-kernel grid barriers. Split-K(x2) GEMM tiles identical to R3.
constexpr int BT = 64;  // block tile (rows and cols)
constexpr int KT = 64;  // k sub-tile
constexpr int LS = 68;  // LDS row stride in floats (68*4=272 B, 16B aligned)

// ---------------------------------------------------------------------------
// Device-scope grid barrier. flags[] lives in ws: re-poisoned to 0xAAAAAAAA
// (negative as int) before every launch, so `< token` reads "not arrived"
// for both poison and zero initial states. Tokens increase monotonically per
// barrier so stragglers polling an old token are fine (monotone >=).
// Exactly 256 blocks x 256 threads: thread t polls flags[t].
// ---------------------------------------------------------------------------
__device__ __forceinline__ void grid_barrier(int* flags, int token) {
    __syncthreads();
    __threadfence();   // make this block's prior global writes device-visible
    if (threadIdx.x == 0)
        __hip_atomic_store(&flags[blockIdx.x], token,
                           __ATOMIC_RELEASE, __HIP_MEMORY_SCOPE_AGENT);
    while (__hip_atomic_load(&flags[threadIdx.x],
                             __ATOMIC_ACQUIRE, __HIP_MEMORY_SCOPE_AGENT) < token) {}
    __syncthreads();
    __threadfence();
}

// ---------------------------------------------------------------------------
// 64x64 fp32 tile GEMM over K range [k0, k0+128): C = opA(A) @ B^T (+bias).
// SUMRELU_A: A := relu(A0 + A1) elementwise (fused layer-1 activation).
// bias == nullptr -> no bias (non-zero K chunk). Shared tiles passed in so
// both call sites share one LDS allocation. Ends with __syncthreads().
// ---------------------------------------------------------------------------
template <bool SUMRELU_A>
__device__ __forceinline__ void gemm_tile_sk(const float* __restrict__ A0,
                                             const float* __restrict__ A1,
                                             const float* __restrict__ B,
                                             const float* __restrict__ bias,
                                             float* __restrict__ C,
                                             int rowBase, int colBase, int k0,
                                             float (*As)[LS], float (*Bs)[LS]) {
    const int t = threadIdx.x;
    const int tx = t & 15;   // micro col group (16 x 4 cols = 64)
    const int ty = t >> 4;   // micro row group (16 x 4 rows = 64)

    float acc[4][4] = {};

    for (int kt = k0; kt < k0 + 128; kt += KT) {
#pragma unroll
        for (int p = 0; p < 4; p++) {
            int idx = p * 256 + t;
            int r = idx >> 4;    // 0..63 row within tile
            int k4 = idx & 15;   // float4 index along k
            int off = (rowBase + r) * 256 + kt + k4 * 4;
            float4 av = *(const float4*)&A0[off];
            if (SUMRELU_A) {
                float4 a1 = *(const float4*)&A1[off];
                av.x = fmaxf(av.x + a1.x, 0.f);
                av.y = fmaxf(av.y + a1.y, 0.f);
                av.z = fmaxf(av.z + a1.z, 0.f);
                av.w = fmaxf(av.w + a1.w, 0.f);
            }
            float4 bv = *(const float4*)&B[(colBase + r) * 256 + kt + k4 * 4];
            As[k4 * 4 + 0][r] = av.x; As[k4 * 4 + 1][r] = av.y;
            As[k4 * 4 + 2][r] = av.z; As[k4 * 4 + 3][r] = av.w;
            Bs[k4 * 4 + 0][r] = bv.x; Bs[k4 * 4 + 1][r] = bv.y;
            Bs[k4 * 4 + 2][r] = bv.z; Bs[k4 * 4 + 3][r] = bv.w;
        }
        __syncthreads();

#pragma unroll 16
        for (int k = 0; k < KT; k++) {
            float4 a4 = *(const float4*)&As[k][ty * 4];
            float4 b4 = *(const float4*)&Bs[k][tx * 4];
            float av[4] = {a4.x, a4.y, a4.z, a4.w};
            float bv[4] = {b4.x, b4.y, b4.z, b4.w};
#pragma unroll
            for (int i = 0; i < 4; i++)
#pragma unroll
                for (int j = 0; j < 4; j++)
                    acc[i][j] = fmaf(av[i], bv[j], acc[i][j]);
        }
        __syncthreads();
    }

    float bb[4] = {0.f, 0.f, 0.f, 0.f};
    if (bias) {
        float4 bq = *(const float4*)&bias[colBase + tx * 4];
        bb[0] = bq.x; bb[1] = bq.y; bb[2] = bq.z; bb[3] = bq.w;
    }
#pragma unroll
    for (int i = 0; i < 4; i++) {
        int row = rowBase + ty * 4 + i;
        float4 o;
        o.x = acc[i][0] + bb[0];
        o.y = acc[i][1] + bb[1];
        o.z = acc[i][2] + bb[2];
        o.w = acc[i][3] + bb[3];
        *(float4*)&C[row * 256 + colBase + tx * 4] = o;
    }
}

// Block decode for 256 split-K GEMM blocks:
//   chunk = bid&1, head = (bid>>1)&1, colTile = (bid>>2)&3, rowTile = bid>>4
#define DECODE_GEMM(bid, chunk, head, rowBase, colBase, k0) \
    int chunk = (bid) & 1;                                  \
    int head  = ((bid) >> 1) & 1;                           \
    int colBase = (((bid) >> 2) & 3) * BT;                  \
    int rowBase = ((bid) >> 4) * BT;                        \
    int k0 = chunk * 128;

// ---------------------------------------------------------------------------
// Fused kernel: phase1 (layer1 GEMM + 4-row moment partials + out zero) ->
// barrier -> phase2 (layer2 GEMM + 256->16 moment fold on blocks 0..15) ->
// barrier -> phase3 (epilogue, 4 rows/block).
// ---------------------------------------------------------------------------
__global__ __launch_bounds__(256)
void fused_club(const float* __restrict__ x,
                const float* __restrict__ y, const float* __restrict__ z,
                const float* __restrict__ w1m, const float* __restrict__ b1m,
                const float* __restrict__ w2m, const float* __restrict__ b2m,
                const float* __restrict__ w1l, const float* __restrict__ b1l,
                const float* __restrict__ w2l, const float* __restrict__ b2l,
                float* __restrict__ hm0, float* __restrict__ hm1,
                float* __restrict__ hl0, float* __restrict__ hl1,
                float* __restrict__ mu0, float* __restrict__ mu1,
                float* __restrict__ lv0, float* __restrict__ lv1,
                float* __restrict__ pA1, float* __restrict__ pB1,
                float* __restrict__ pA2, float* __restrict__ pB2,
                int* flags, float* __restrict__ out) {
    __shared__ float As[KT][LS];
    __shared__ float Bs[KT][LS];
    __shared__ float red[4];
    const int bid = blockIdx.x;
    const int t = threadIdx.x;

    // ---------------- Phase 1: layer-1 GEMM + moment partials ----------------
    {
        DECODE_GEMM(bid, chunk, head, rowBase, colBase, k0)
        const float* Bw = head ? w1l : w1m;
        const float* bias = chunk ? nullptr : (head ? b1l : b1m);
        float* C = head ? (chunk ? hl1 : hl0) : (chunk ? hm1 : hm0);
        gemm_tile_sk<false>(x, nullptr, Bw, bias, C, rowBase, colBase, k0, As, Bs);

        // moment partials over rows [4*bid, 4*bid+4): pA1 = sum(y^2+z^2), pB1 = sum(y+z)
        float sA = 0.f, sB = 0.f;
        int base = bid * 4 * 256 + t;
#pragma unroll
        for (int j = 0; j < 4; j++) {
            float yv = y[base + j * 256];
            float zv = z[base + j * 256];
            sA += yv * yv + zv * zv;
            sB += yv + zv;
        }
        pA1[bid * 256 + t] = sA;
        pB1[bid * 256 + t] = sB;
        if (bid == 0 && t == 0) out[0] = 0.f;   // zero accumulator before phase 3
    }
    grid_barrier(flags, 1);

    // ---------------- Phase 2: layer-2 GEMM + moment fold 256->16 ----------------
    {
        DECODE_GEMM(bid, chunk, head, rowBase, colBase, k0)
        const float* A0 = head ? hl0 : hm0;
        const float* A1 = head ? hl1 : hm1;
        const float* Bw = head ? w2l : w2m;
        const float* bias = chunk ? nullptr : (head ? b2l : b2m);
        float* C = head ? (chunk ? lv1 : lv0) : (chunk ? mu1 : mu0);
        gemm_tile_sk<true>(A0, A1, Bw, bias, C, rowBase, colBase, k0, As, Bs);

        if (bid < 16) {
            float sA = 0.f, sB = 0.f;
#pragma unroll
            for (int s = 0; s < 16; s++) {
                int o = (bid * 16 + s) * 256 + t;
                sA += pA1[o];
                sB += pB1[o];
            }
            pA2[bid * 256 + t] = sA;
            pB2[bid * 256 + t] = sB;
        }
    }
    grid_barrier(flags, 2);

    // ---------------- Phase 3: epilogue, rows [4*bid, 4*bid+4) ----------------
    {
        int lane = t & 63, wave = t >> 6;
        float mA = 0.f, mB = 0.f;
#pragma unroll
        for (int g = 0; g < 16; g++) {
            mA += pA2[g * 256 + t];
            mB += pB2[g * 256 + t];
        }
        mA *= (1.f / 1024.f);   // mean_j (y^2+z^2)
        mB *= (1.f / 1024.f);   // mean_j (y+z)

        float blockSum = 0.f;
        for (int r = 0; r < 4; r++) {
            int o = (bid * 4 + r) * 256 + t;
            float m  = mu0[o] + mu1[o];
            float lv = tanhf(lv0[o] + lv1[o]);
            float iv = 0.5f * expf(-lv);       // 1/(2*exp(logvar))
            float yv = y[o];
            float zv = z[o];
            float Mt = mA - 2.f * m * mB + 2.f * m * m;   // mean_j sq
            float dy = m - yv, dz = m - zv;
            float term = iv * (Mt - dy * dy - dz * dz);   // positive - negative
#pragma unroll
            for (int mask = 32; mask; mask >>= 1)
                term += __shfl_xor(term, mask, 64);
            if (lane == 0) red[wave] = term;
            __syncthreads();
            if (t == 0) {
                float rs = red[0] + red[1] + red[2] + red[3];
                blockSum += fmaxf(rs, 0.f);
            }
            __syncthreads();
        }
        if (t == 0) atomicAdd(out, blockSum * (1.f / 1024.f));
    }
}

// ---------------------------------------------------------------------------
extern "C" void kernel_launch(void* const* d_in, const int* in_sizes, int n_in,
                              void* d_out, int out_size, void* d_ws, size_t ws_size,
                              hipStream_t stream) {
    const float* x   = (const float*)d_in[0];
    const float* y   = (const float*)d_in[1];
    const float* zs  = (const float*)d_in[2];
    const float* w1m = (const float*)d_in[3];
    const float* b1m = (const float*)d_in[4];
    const float* w2m = (const float*)d_in[5];
    const float* b2m = (const float*)d_in[6];
    const float* w1l = (const float*)d_in[7];
    const float* b1l = (const float*)d_in[8];
    const float* w2l = (const float*)d_in[9];
    const float* b2l = (const float*)d_in[10];
    float* out = (float*)d_out;

    char* ws = (char*)d_ws;
    int*   flags = (int*)(ws);                       // 256 x 4B = 1 KB
    float* pA2 = (float*)(ws + (16u << 10));         // 16 KB
    float* pB2 = (float*)(ws + (32u << 10));         // 16 KB
    float* pA1 = (float*)(ws + (256u << 10));        // 256 KB
    float* pB1 = (float*)(ws + (512u << 10));        // 256 KB
    float* buf = (float*)(ws + (1u << 20));          // 8 x 1 MB fp32 buffers
    const unsigned MB = (1u << 20) / 4;              // floats per MB
    float* hm0 = buf + 0 * MB;
    float* hm1 = buf + 1 * MB;
    float* hl0 = buf + 2 * MB;
    float* hl1 = buf + 3 * MB;
    float* mu0 = buf + 4 * MB;
    float* mu1 = buf + 5 * MB;
    float* lv0 = buf + 6 * MB;
    float* lv1 = buf + 7 * MB;

    fused_club<<<256, 256, 0, stream>>>(x, y, zs,
                                        w1m, b1m, w2m, b2m,
                                        w1l, b1l, w2l, b2l,
                                        hm0, hm1, hl0, hl1,
                                        mu0, mu1, lv0, lv1,
                                        pA1, pB1, pA2, pB2,
                                        flags, out);
}

// Round 5
// 104.807 us; speedup vs baseline: 2.0757x; 2.0757x over previous
//
#include <hip/hip_runtime.h>
#include <math.h>

// N=1024, X_DIM=HID=Y_DIM=256. 3 launches (R3 structure — grid-barrier fusion
// regressed 2x in R4 via L2-invalidate storms from agent-scope spin loops).
// This round: LDS write-conflict swizzle + moments fused into K1 GEMM blocks.
constexpr int BT = 64;  // block tile (rows and cols)
constexpr int KT = 64;  // k sub-tile
constexpr int LS = 68;  // LDS row stride in floats (68*4=272 B, 16B aligned)

// ---------------------------------------------------------------------------
// 64x64 fp32 tile GEMM over K range [k0, k0+128): C = opA(A) @ B^T (+bias).
// SUMRELU_A: A := relu(A0 + A1) elementwise (fused layer-1 activation).
// bias == nullptr -> no bias (non-zero K chunk).
//
// LDS swizzle: element (k, m) stored at As[k][(m + 4*(k>>2)) & 63].
// Write banks: (20*k4 + tq) % 32 -> 32 distinct, 2 lanes/bank (free).
// Without swizzle banks were (16*k4 + tq) % 32 -> 8-way conflict (R4 counter:
// 1.84M SQ_LDS_BANK_CONFLICT cycles). Reads stay aligned float4 (ds_read_b128).
// ---------------------------------------------------------------------------
template <bool SUMRELU_A>
__device__ __forceinline__ void gemm_tile_sk(const float* __restrict__ A0,
                                             const float* __restrict__ A1,
                                             const float* __restrict__ B,
                                             const float* __restrict__ bias,
                                             float* __restrict__ C,
                                             int rowBase, int colBase, int k0) {
    const int t = threadIdx.x;
    const int tx = t & 15;   // micro col group (16 x 4 cols = 64)
    const int ty = t >> 4;   // micro row group (16 x 4 rows = 64)

    __shared__ float As[KT][LS];  // As[k][swizzled m]
    __shared__ float Bs[KT][LS];  // Bs[k][swizzled n]

    float acc[4][4] = {};

    for (int kt = k0; kt < k0 + 128; kt += KT) {
#pragma unroll
        for (int p = 0; p < 4; p++) {
            int idx = p * 256 + t;
            int r = idx >> 4;    // 0..63 row within tile
            int k4 = idx & 15;   // float4 index along k
            int off = (rowBase + r) * 256 + kt + k4 * 4;
            float4 av = *(const float4*)&A0[off];
            if (SUMRELU_A) {
                float4 a1 = *(const float4*)&A1[off];
                av.x = fmaxf(av.x + a1.x, 0.f);
                av.y = fmaxf(av.y + a1.y, 0.f);
                av.z = fmaxf(av.z + a1.z, 0.f);
                av.w = fmaxf(av.w + a1.w, 0.f);
            }
            float4 bv = *(const float4*)&B[(colBase + r) * 256 + kt + k4 * 4];
            int rs = (r + 4 * k4) & 63;   // swizzled column
            As[k4 * 4 + 0][rs] = av.x; As[k4 * 4 + 1][rs] = av.y;
            As[k4 * 4 + 2][rs] = av.z; As[k4 * 4 + 3][rs] = av.w;
            Bs[k4 * 4 + 0][rs] = bv.x; Bs[k4 * 4 + 1][rs] = bv.y;
            Bs[k4 * 4 + 2][rs] = bv.z; Bs[k4 * 4 + 3][rs] = bv.w;
        }
        __syncthreads();

#pragma unroll 16
        for (int k = 0; k < KT; k++) {
            int sa = (ty * 4 + (k & ~3)) & 63;   // un-swizzle (const fold per unrolled k)
            int sb = (tx * 4 + (k & ~3)) & 63;
            float4 a4 = *(const float4*)&As[k][sa];
            float4 b4 = *(const float4*)&Bs[k][sb];
            float av[4] = {a4.x, a4.y, a4.z, a4.w};
            float bv[4] = {b4.x, b4.y, b4.z, b4.w};
#pragma unroll
            for (int i = 0; i < 4; i++)
#pragma unroll
                for (int j = 0; j < 4; j++)
                    acc[i][j] = fmaf(av[i], bv[j], acc[i][j]);
        }
        __syncthreads();
    }

    float bb[4] = {0.f, 0.f, 0.f, 0.f};
    if (bias) {
        float4 bq = *(const float4*)&bias[colBase + tx * 4];
        bb[0] = bq.x; bb[1] = bq.y; bb[2] = bq.z; bb[3] = bq.w;
    }
#pragma unroll
    for (int i = 0; i < 4; i++) {
        int row = rowBase + ty * 4 + i;
        float4 o;
        o.x = acc[i][0] + bb[0];
        o.y = acc[i][1] + bb[1];
        o.z = acc[i][2] + bb[2];
        o.w = acc[i][3] + bb[3];
        *(float4*)&C[row * 256 + colBase + tx * 4] = o;
    }
}

// Block decode for 256 split-K GEMM blocks:
//   chunk = bid&1, head = (bid>>1)&1, colTile = (bid>>2)&3, rowTile = bid>>4
#define DECODE_GEMM(bid, chunk, head, rowBase, colBase, k0) \
    int chunk = (bid) & 1;                                  \
    int head  = ((bid) >> 1) & 1;                           \
    int colBase = (((bid) >> 2) & 3) * BT;                  \
    int rowBase = ((bid) >> 4) * BT;                        \
    int k0 = chunk * 128;

// ---------------------------------------------------------------------------
// K1: layer-1 split-K GEMM + per-block 4-row moment partials + out zero.
// Exactly 256 blocks (no tail blocks).
// ---------------------------------------------------------------------------
__global__ __launch_bounds__(256)
void k1_layer1(const float* __restrict__ x,
               const float* __restrict__ w1m, const float* __restrict__ w1l,
               const float* __restrict__ b1m, const float* __restrict__ b1l,
               float* __restrict__ hm0, float* __restrict__ hm1,
               float* __restrict__ hl0, float* __restrict__ hl1,
               const float* __restrict__ y, const float* __restrict__ z,
               float* __restrict__ pA1, float* __restrict__ pB1,
               float* __restrict__ out) {
    int bid = blockIdx.x;
    int t = threadIdx.x;
    DECODE_GEMM(bid, chunk, head, rowBase, colBase, k0)
    const float* Bw = head ? w1l : w1m;
    const float* bias = chunk ? nullptr : (head ? b1l : b1m);
    float* C = head ? (chunk ? hl1 : hl0) : (chunk ? hm1 : hm0);
    gemm_tile_sk<false>(x, nullptr, Bw, bias, C, rowBase, colBase, k0);

    // moment partials over rows [4*bid, 4*bid+4): pA1=sum(y^2+z^2), pB1=sum(y+z)
    float sA = 0.f, sB = 0.f;
    int base = bid * 4 * 256 + t;
#pragma unroll
    for (int j = 0; j < 4; j++) {
        float yv = y[base + j * 256];
        float zv = z[base + j * 256];
        sA += yv * yv + zv * zv;
        sB += yv + zv;
    }
    pA1[bid * 256 + t] = sA;
    pB1[bid * 256 + t] = sB;
    if (bid == 0 && t == 0) out[0] = 0.f;   // zero accumulator before K3
}

// ---------------------------------------------------------------------------
// K2: layer-2 split-K GEMM; A = relu(h0+h1) fused in staging. 256 blocks.
// Blocks 0..15 also fold the 256 moment partials down to 16.
// ---------------------------------------------------------------------------
__global__ __launch_bounds__(256)
void k2_layer2(const float* __restrict__ hm0, const float* __restrict__ hm1,
               const float* __restrict__ hl0, const float* __restrict__ hl1,
               const float* __restrict__ w2m, const float* __restrict__ w2l,
               const float* __restrict__ b2m, const float* __restrict__ b2l,
               float* __restrict__ mu0, float* __restrict__ mu1,
               float* __restrict__ lv0, float* __restrict__ lv1,
               const float* __restrict__ pA1, const float* __restrict__ pB1,
               float* __restrict__ pA2, float* __restrict__ pB2) {
    int bid = blockIdx.x;
    int t = threadIdx.x;
    DECODE_GEMM(bid, chunk, head, rowBase, colBase, k0)
    const float* A0 = head ? hl0 : hm0;
    const float* A1 = head ? hl1 : hm1;
    const float* Bw = head ? w2l : w2m;
    const float* bias = chunk ? nullptr : (head ? b2l : b2m);
    float* C = head ? (chunk ? lv1 : lv0) : (chunk ? mu1 : mu0);
    gemm_tile_sk<true>(A0, A1, Bw, bias, C, rowBase, colBase, k0);

    if (bid < 16) {
        float sA = 0.f, sB = 0.f;
#pragma unroll
        for (int s = 0; s < 16; s++) {
            int o = (bid * 16 + s) * 256 + t;
            sA += pA1[o];
            sB += pB1[o];
        }
        pA2[bid * 256 + t] = sA;
        pB2[bid * 256 + t] = sB;
    }
}

// ---------------------------------------------------------------------------
// K3: epilogue. mu = mu0+mu1, lv_pre = lv0+lv1; fold 16 moment partials;
// per row i: diff = sum_o iv*(M - (mu-y)^2 - (mu-z)^2); out += relu(diff)/N.
// 256 blocks x 4 rows; thread = output dim.
// ---------------------------------------------------------------------------
__global__ __launch_bounds__(256)
void k3_epilogue(const float* __restrict__ mu0, const float* __restrict__ mu1,
                 const float* __restrict__ lv0, const float* __restrict__ lv1,
                 const float* __restrict__ y, const float* __restrict__ z,
                 const float* __restrict__ pA2, const float* __restrict__ pB2,
                 float* __restrict__ out) {
    __shared__ float red[4];
    int t = threadIdx.x;
    int lane = t & 63, wave = t >> 6;

    float mA = 0.f, mB = 0.f;
#pragma unroll
    for (int g = 0; g < 16; g++) {
        mA += pA2[g * 256 + t];
        mB += pB2[g * 256 + t];
    }
    mA *= (1.f / 1024.f);   // mean_j (y^2+z^2)
    mB *= (1.f / 1024.f);   // mean_j (y+z)

    float blockSum = 0.f;
    for (int r = 0; r < 4; r++) {
        int o = (blockIdx.x * 4 + r) * 256 + t;
        float m  = mu0[o] + mu1[o];
        float lv = tanhf(lv0[o] + lv1[o]);
        float iv = 0.5f * expf(-lv);       // 1/(2*exp(logvar))
        float yv = y[o];
        float zv = z[o];
        float Mt = mA - 2.f * m * mB + 2.f * m * m;   // mean_j sq
        float dy = m - yv, dz = m - zv;
        float term = iv * (Mt - dy * dy - dz * dz);   // positive - negative
#pragma unroll
        for (int mask = 32; mask; mask >>= 1)
            term += __shfl_xor(term, mask, 64);
        if (lane == 0) red[wave] = term;
        __syncthreads();
        if (t == 0) {
            float rs = red[0] + red[1] + red[2] + red[3];
            blockSum += fmaxf(rs, 0.f);
        }
        __syncthreads();
    }
    if (t == 0) atomicAdd(out, blockSum * (1.f / 1024.f));
}

// ---------------------------------------------------------------------------
extern "C" void kernel_launch(void* const* d_in, const int* in_sizes, int n_in,
                              void* d_out, int out_size, void* d_ws, size_t ws_size,
                              hipStream_t stream) {
    const float* x   = (const float*)d_in[0];
    const float* y   = (const float*)d_in[1];
    const float* zs  = (const float*)d_in[2];
    const float* w1m = (const float*)d_in[3];
    const float* b1m = (const float*)d_in[4];
    const float* w2m = (const float*)d_in[5];
    const float* b2m = (const float*)d_in[6];
    const float* w1l = (const float*)d_in[7];
    const float* b1l = (const float*)d_in[8];
    const float* w2l = (const float*)d_in[9];
    const float* b2l = (const float*)d_in[10];
    float* out = (float*)d_out;

    char* ws = (char*)d_ws;
    float* pA2 = (float*)(ws);                       // 16x256 f32 = 16 KB
    float* pB2 = (float*)(ws + (16u << 10));         // 16 KB
    float* pA1 = (float*)(ws + (256u << 10));        // 256x256 f32 = 256 KB
    float* pB1 = (float*)(ws + (512u << 10));        // 256 KB
    float* buf = (float*)(ws + (1u << 20));          // 8 x 1 MB fp32 buffers
    const unsigned MB = (1u << 20) / 4;              // floats per MB
    float* hm0 = buf + 0 * MB;
    float* hm1 = buf + 1 * MB;
    float* hl0 = buf + 2 * MB;
    float* hl1 = buf + 3 * MB;
    float* mu0 = buf + 4 * MB;
    float* mu1 = buf + 5 * MB;
    float* lv0 = buf + 6 * MB;
    float* lv1 = buf + 7 * MB;

    k1_layer1<<<256, 256, 0, stream>>>(x, w1m, w1l, b1m, b1l,
                                       hm0, hm1, hl0, hl1,
                                       y, zs, pA1, pB1, out);
    k2_layer2<<<256, 256, 0, stream>>>(hm0, hm1, hl0, hl1,
                                       w2m, w2l, b2m, b2l,
                                       mu0, mu1, lv0, lv1,
                                       pA1, pB1, pA2, pB2);
    k3_epilogue<<<256, 256, 0, stream>>>(mu0, mu1, lv0, lv1,
                                         y, zs, pA2, pB2, out);
}

// Round 6
// 101.988 us; speedup vs baseline: 2.1331x; 1.0276x over previous
//
#include <hip/hip_runtime.h>
#include <math.h>

// N=1024, X_DIM=HID=Y_DIM=256. 3 launches, split-K(x2), 256 blocks/launch.
// This round: GEMM bodies use MFMA bf16 with Dekker split-fp32 emulation
// (hi*hi + hi*lo + lo*hi), replacing the LDS-read-bound fp32 vector path.
constexpr int KT = 64;   // k sub-tile staged in LDS
constexpr int LSB = 72;  // bf16 LDS row stride: 144 B = 36 words -> 2-way banks

typedef short bf16x8 __attribute__((ext_vector_type(8)));
typedef float f32x4  __attribute__((ext_vector_type(4)));

__device__ __forceinline__ unsigned short f2bf_rne(float f) {
    unsigned u = __float_as_uint(f);
    unsigned r = (u + 0x7fff + ((u >> 16) & 1)) >> 16;
    return (unsigned short)r;
}
__device__ __forceinline__ float bf2f(unsigned short h) {
    return __uint_as_float(((unsigned)h) << 16);
}

// ---------------------------------------------------------------------------
// 64x64 tile GEMM over K range [k0, k0+128): C = opA(A) @ B^T (+bias).
// SUMRELU_A: A := relu(A0 + A1) elementwise (fused layer-1 activation).
// MFMA 16x16x32 bf16, split-fp32: per fp32 operand x, hi=bf16(x),
// lo=bf16(x-hi) (Dekker split, exact); acc += Ah*Bh + Ah*Bl + Al*Bh.
// Wave w handles rows [16w,16w+16); 4 col-chunks of 16; acc = 4 x f32x4.
// Fragment layouts (HW-verified, learn_hip m89/m120):
//   A/B: [m|n = lane&15][k = (lane>>4)*8 + j]   (8 contiguous bf16 = b128)
//   C/D: col = lane&15, row = (lane>>4)*4 + reg
// ---------------------------------------------------------------------------
template <bool SUMRELU_A>
__device__ __forceinline__ void gemm_tile_mfma(const float* __restrict__ A0,
                                               const float* __restrict__ A1,
                                               const float* __restrict__ B,
                                               const float* __restrict__ bias,
                                               float* __restrict__ C,
                                               int rowBase, int colBase, int k0) {
    const int t = threadIdx.x;
    const int w    = t >> 6;        // wave 0..3
    const int lane = t & 63;
    const int quad = lane >> 4;
    const int mr   = lane & 15;

    __shared__ __align__(16) unsigned short Ah[64][LSB];
    __shared__ __align__(16) unsigned short Al[64][LSB];
    __shared__ __align__(16) unsigned short Bh[64][LSB];
    __shared__ __align__(16) unsigned short Bl[64][LSB];

    f32x4 acc[4] = {{0.f, 0.f, 0.f, 0.f}, {0.f, 0.f, 0.f, 0.f},
                    {0.f, 0.f, 0.f, 0.f}, {0.f, 0.f, 0.f, 0.f}};

    for (int kt = k0; kt < k0 + 128; kt += KT) {
        // ---- stage 64x64 fp32 tiles as bf16 hi/lo into LDS ----
#pragma unroll
        for (int p = 0; p < 4; p++) {
            int idx = p * 256 + t;
            int r = idx >> 4;    // 0..63 row within tile
            int k4 = idx & 15;   // float4 index along k
            int off = (rowBase + r) * 256 + kt + k4 * 4;
            float4 av = *(const float4*)&A0[off];
            if (SUMRELU_A) {
                float4 a1 = *(const float4*)&A1[off];
                av.x = fmaxf(av.x + a1.x, 0.f);
                av.y = fmaxf(av.y + a1.y, 0.f);
                av.z = fmaxf(av.z + a1.z, 0.f);
                av.w = fmaxf(av.w + a1.w, 0.f);
            }
            float4 bv = *(const float4*)&B[(colBase + r) * 256 + kt + k4 * 4];

            ushort4 ahv, alv, bhv, blv;
            ahv.x = f2bf_rne(av.x); alv.x = f2bf_rne(av.x - bf2f(ahv.x));
            ahv.y = f2bf_rne(av.y); alv.y = f2bf_rne(av.y - bf2f(ahv.y));
            ahv.z = f2bf_rne(av.z); alv.z = f2bf_rne(av.z - bf2f(ahv.z));
            ahv.w = f2bf_rne(av.w); alv.w = f2bf_rne(av.w - bf2f(ahv.w));
            bhv.x = f2bf_rne(bv.x); blv.x = f2bf_rne(bv.x - bf2f(bhv.x));
            bhv.y = f2bf_rne(bv.y); blv.y = f2bf_rne(bv.y - bf2f(bhv.y));
            bhv.z = f2bf_rne(bv.z); blv.z = f2bf_rne(bv.z - bf2f(bhv.z));
            bhv.w = f2bf_rne(bv.w); blv.w = f2bf_rne(bv.w - bf2f(bhv.w));

            *(ushort4*)&Ah[r][k4 * 4] = ahv;
            *(ushort4*)&Al[r][k4 * 4] = alv;
            *(ushort4*)&Bh[r][k4 * 4] = bhv;
            *(ushort4*)&Bl[r][k4 * 4] = blv;
        }
        __syncthreads();

        // ---- MFMA inner loop over this k-tile (two k32 chunks) ----
#pragma unroll
        for (int kk = 0; kk < KT; kk += 32) {
            int ko = kk + quad * 8;
            bf16x8 ah = *(const bf16x8*)&Ah[w * 16 + mr][ko];
            bf16x8 al = *(const bf16x8*)&Al[w * 16 + mr][ko];
#pragma unroll
            for (int c = 0; c < 4; c++) {
                bf16x8 bh = *(const bf16x8*)&Bh[c * 16 + mr][ko];
                bf16x8 bl = *(const bf16x8*)&Bl[c * 16 + mr][ko];
                acc[c] = __builtin_amdgcn_mfma_f32_16x16x32_bf16(ah, bh, acc[c], 0, 0, 0);
                acc[c] = __builtin_amdgcn_mfma_f32_16x16x32_bf16(ah, bl, acc[c], 0, 0, 0);
                acc[c] = __builtin_amdgcn_mfma_f32_16x16x32_bf16(al, bh, acc[c], 0, 0, 0);
            }
        }
        __syncthreads();
    }

    float bcol[4] = {0.f, 0.f, 0.f, 0.f};
    if (bias) {
#pragma unroll
        for (int c = 0; c < 4; c++) bcol[c] = bias[colBase + c * 16 + mr];
    }
#pragma unroll
    for (int c = 0; c < 4; c++) {
#pragma unroll
        for (int reg = 0; reg < 4; reg++) {
            int rg = rowBase + w * 16 + quad * 4 + reg;
            int cg = colBase + c * 16 + mr;
            C[rg * 256 + cg] = acc[c][reg] + bcol[c];
        }
    }
}

// Block decode for 256 split-K GEMM blocks:
//   chunk = bid&1, head = (bid>>1)&1, colTile = (bid>>2)&3, rowTile = bid>>4
#define DECODE_GEMM(bid, chunk, head, rowBase, colBase, k0) \
    int chunk = (bid) & 1;                                  \
    int head  = ((bid) >> 1) & 1;                           \
    int colBase = (((bid) >> 2) & 3) * 64;                  \
    int rowBase = ((bid) >> 4) * 64;                        \
    int k0 = chunk * 128;

// ---------------------------------------------------------------------------
// K1: layer-1 split-K GEMM + per-block 4-row moment partials + out zero.
// ---------------------------------------------------------------------------
__global__ __launch_bounds__(256)
void k1_layer1(const float* __restrict__ x,
               const float* __restrict__ w1m, const float* __restrict__ w1l,
               const float* __restrict__ b1m, const float* __restrict__ b1l,
               float* __restrict__ hm0, float* __restrict__ hm1,
               float* __restrict__ hl0, float* __restrict__ hl1,
               const float* __restrict__ y, const float* __restrict__ z,
               float* __restrict__ pA1, float* __restrict__ pB1,
               float* __restrict__ out) {
    int bid = blockIdx.x;
    int t = threadIdx.x;
    DECODE_GEMM(bid, chunk, head, rowBase, colBase, k0)
    const float* Bw = head ? w1l : w1m;
    const float* bias = chunk ? nullptr : (head ? b1l : b1m);
    float* C = head ? (chunk ? hl1 : hl0) : (chunk ? hm1 : hm0);
    gemm_tile_mfma<false>(x, nullptr, Bw, bias, C, rowBase, colBase, k0);

    // moment partials over rows [4*bid, 4*bid+4): pA1=sum(y^2+z^2), pB1=sum(y+z)
    float sA = 0.f, sB = 0.f;
    int base = bid * 4 * 256 + t;
#pragma unroll
    for (int j = 0; j < 4; j++) {
        float yv = y[base + j * 256];
        float zv = z[base + j * 256];
        sA += yv * yv + zv * zv;
        sB += yv + zv;
    }
    pA1[bid * 256 + t] = sA;
    pB1[bid * 256 + t] = sB;
    if (bid == 0 && t == 0) out[0] = 0.f;   // zero accumulator before K3
}

// ---------------------------------------------------------------------------
// K2: layer-2 split-K GEMM; A = relu(h0+h1) fused in staging. 256 blocks.
// Blocks 0..15 also fold the 256 moment partials down to 16.
// ---------------------------------------------------------------------------
__global__ __launch_bounds__(256)
void k2_layer2(const float* __restrict__ hm0, const float* __restrict__ hm1,
               const float* __restrict__ hl0, const float* __restrict__ hl1,
               const float* __restrict__ w2m, const float* __restrict__ w2l,
               const float* __restrict__ b2m, const float* __restrict__ b2l,
               float* __restrict__ mu0, float* __restrict__ mu1,
               float* __restrict__ lv0, float* __restrict__ lv1,
               const float* __restrict__ pA1, const float* __restrict__ pB1,
               float* __restrict__ pA2, float* __restrict__ pB2) {
    int bid = blockIdx.x;
    int t = threadIdx.x;
    DECODE_GEMM(bid, chunk, head, rowBase, colBase, k0)
    const float* A0 = head ? hl0 : hm0;
    const float* A1 = head ? hl1 : hm1;
    const float* Bw = head ? w2l : w2m;
    const float* bias = chunk ? nullptr : (head ? b2l : b2m);
    float* C = head ? (chunk ? lv1 : lv0) : (chunk ? mu1 : mu0);
    gemm_tile_mfma<true>(A0, A1, Bw, bias, C, rowBase, colBase, k0);

    if (bid < 16) {
        float sA = 0.f, sB = 0.f;
#pragma unroll
        for (int s = 0; s < 16; s++) {
            int o = (bid * 16 + s) * 256 + t;
            sA += pA1[o];
            sB += pB1[o];
        }
        pA2[bid * 256 + t] = sA;
        pB2[bid * 256 + t] = sB;
    }
}

// ---------------------------------------------------------------------------
// K3: epilogue. mu = mu0+mu1, lv_pre = lv0+lv1; fold 16 moment partials;
// per row i: diff = sum_o iv*(M - (mu-y)^2 - (mu-z)^2); out += relu(diff)/N.
// ---------------------------------------------------------------------------
__global__ __launch_bounds__(256)
void k3_epilogue(const float* __restrict__ mu0, const float* __restrict__ mu1,
                 const float* __restrict__ lv0, const float* __restrict__ lv1,
                 const float* __restrict__ y, const float* __restrict__ z,
                 const float* __restrict__ pA2, const float* __restrict__ pB2,
                 float* __restrict__ out) {
    __shared__ float red[4];
    int t = threadIdx.x;
    int lane = t & 63, wave = t >> 6;

    float mA = 0.f, mB = 0.f;
#pragma unroll
    for (int g = 0; g < 16; g++) {
        mA += pA2[g * 256 + t];
        mB += pB2[g * 256 + t];
    }
    mA *= (1.f / 1024.f);   // mean_j (y^2+z^2)
    mB *= (1.f / 1024.f);   // mean_j (y+z)

    float blockSum = 0.f;
    for (int r = 0; r < 4; r++) {
        int o = (blockIdx.x * 4 + r) * 256 + t;
        float m  = mu0[o] + mu1[o];
        float lv = tanhf(lv0[o] + lv1[o]);
        float iv = 0.5f * expf(-lv);       // 1/(2*exp(logvar))
        float yv = y[o];
        float zv = z[o];
        float Mt = mA - 2.f * m * mB + 2.f * m * m;   // mean_j sq
        float dy = m - yv, dz = m - zv;
        float term = iv * (Mt - dy * dy - dz * dz);   // positive - negative
#pragma unroll
        for (int mask = 32; mask; mask >>= 1)
            term += __shfl_xor(term, mask, 64);
        if (lane == 0) red[wave] = term;
        __syncthreads();
        if (t == 0) {
            float rs = red[0] + red[1] + red[2] + red[3];
            blockSum += fmaxf(rs, 0.f);
        }
        __syncthreads();
    }
    if (t == 0) atomicAdd(out, blockSum * (1.f / 1024.f));
}

// ---------------------------------------------------------------------------
extern "C" void kernel_launch(void* const* d_in, const int* in_sizes, int n_in,
                              void* d_out, int out_size, void* d_ws, size_t ws_size,
                              hipStream_t stream) {
    const float* x   = (const float*)d_in[0];
    const float* y   = (const float*)d_in[1];
    const float* zs  = (const float*)d_in[2];
    const float* w1m = (const float*)d_in[3];
    const float* b1m = (const float*)d_in[4];
    const float* w2m = (const float*)d_in[5];
    const float* b2m = (const float*)d_in[6];
    const float* w1l = (const float*)d_in[7];
    const float* b1l = (const float*)d_in[8];
    const float* w2l = (const float*)d_in[9];
    const float* b2l = (const float*)d_in[10];
    float* out = (float*)d_out;

    char* ws = (char*)d_ws;
    float* pA2 = (float*)(ws);                       // 16x256 f32 = 16 KB
    float* pB2 = (float*)(ws + (16u << 10));         // 16 KB
    float* pA1 = (float*)(ws + (256u << 10));        // 256x256 f32 = 256 KB
    float* pB1 = (float*)(ws + (512u << 10));        // 256 KB
    float* buf = (float*)(ws + (1u << 20));          // 8 x 1 MB fp32 buffers
    const unsigned MB = (1u << 20) / 4;              // floats per MB
    float* hm0 = buf + 0 * MB;
    float* hm1 = buf + 1 * MB;
    float* hl0 = buf + 2 * MB;
    float* hl1 = buf + 3 * MB;
    float* mu0 = buf + 4 * MB;
    float* mu1 = buf + 5 * MB;
    float* lv0 = buf + 6 * MB;
    float* lv1 = buf + 7 * MB;

    k1_layer1<<<256, 256, 0, stream>>>(x, w1m, w1l, b1m, b1l,
                                       hm0, hm1, hl0, hl1,
                                       y, zs, pA1, pB1, out);
    k2_layer2<<<256, 256, 0, stream>>>(hm0, hm1, hl0, hl1,
                                       w2m, w2l, b2m, b2l,
                                       mu0, mu1, lv0, lv1,
                                       pA1, pB1, pA2, pB2);
    k3_epilogue<<<256, 256, 0, stream>>>(mu0, mu1, lv0, lv1,
                                         y, zs, pA2, pB2, out);
}